// Round 7
// baseline (116.715 us; speedup 1.0000x reference)
//
#include <hip/hip_runtime.h>
#include <math.h>

// Problem: X[16384,64] fp32, W[8192,64] fp32 -> argmin_c ||x-w_c||^2 (int32)
#define EMB     64
#define NTOK    8192
#define NQ      16384
#define TPB     256               // 4 waves: 2 q-halves x 2 c-halves
#define CSPLIT  4
#define CRANGE  (NTOK / CSPLIT)   // 2048 codewords per y-split
#define BQ      128               // query rows per block
#define TILE_C  128               // codewords staged per iteration
#define NT      (CRANGE / TILE_C) // 16 tiles
#define TCH     (TILE_C * EMB)    // halves per tile buffer (8192 = 16KB)
#define NXBLK   (NQ / BQ)         // 128

typedef _Float16 half8 __attribute__((ext_vector_type(8)));
typedef float    f32x4 __attribute__((ext_vector_type(4)));

// async global->LDS DMA, 16B per lane (dest = wave-uniform base + lane*16)
__device__ __forceinline__ void gl2lds16(const _Float16* g, _Float16* l) {
    __builtin_amdgcn_global_load_lds(
        (const __attribute__((address_space(1))) unsigned int*)g,
        (__attribute__((address_space(3))) unsigned int*)l, 16, 0, 0);
}

// monotone float->uint map: m(a) < m(b) iff a < b (no NaNs here)
__device__ __forceinline__ unsigned long long pack_di(float d, int idx) {
    unsigned int u = __float_as_uint(d);
    unsigned int m = (u & 0x80000000u) ? ~u : (u | 0x80000000u);
    return ((unsigned long long)m << 32) | (unsigned int)idx;
}

// ---------------------------------------------------------------------------
// Prep (chunk-parallel): split W into fp16 hi/lo in MFMA-FRAGMENT ORDER
// (one thread per 16B chunk, gtid < 65536), ||w_c||^2 fp32 (one thread per
// row, next 8192 gtids), + init packed[]/cnt[]. Same per-element conversion
// and same fp32 accumulation order as r3-r6 -> bit-identical Wh/Wl/ynorm.
// Chunk u: u = g*128 + kb*64 + lq*16 + r, c = g*16+r, k0 = kb*32+lq*8.
// ---------------------------------------------------------------------------
__global__ void prep_kernel(const float* __restrict__ W,
                            _Float16* __restrict__ Wh, _Float16* __restrict__ Wl,
                            float* __restrict__ ynorm,
                            unsigned long long* __restrict__ packed,
                            int* __restrict__ cnt) {
    const int gtid = blockIdx.x * blockDim.x + threadIdx.x;   // 0..73727
    if (gtid < NQ)    packed[gtid] = ~0ull;
    if (gtid < NXBLK) cnt[gtid] = 0;
    if (gtid < NTOK * 8) {
        const int u  = gtid;
        const int g  = u >> 7, rem = u & 127;
        const int kb = rem >> 6, ln = rem & 63;
        const int r  = ln & 15, lq = ln >> 4;
        const int c  = g * 16 + r;
        const float* wp = W + (size_t)c * EMB + kb * 32 + lq * 8;
        float4 v0 = *(const float4*)wp;
        float4 v1 = *(const float4*)(wp + 4);
        float xv[8] = {v0.x, v0.y, v0.z, v0.w, v1.x, v1.y, v1.z, v1.w};
        half8 h, l;
#pragma unroll
        for (int j = 0; j < 8; ++j) {
            _Float16 hh = (_Float16)xv[j];
            h[j] = hh;
            l[j] = (_Float16)(xv[j] - (float)hh);
        }
        *(half8*)(Wh + (size_t)u * 8) = h;
        *(half8*)(Wl + (size_t)u * 8) = l;
    } else if (gtid < NTOK * 8 + NTOK) {
        const int c = gtid - NTOK * 8;
        const float4* w4 = (const float4*)(W + (size_t)c * EMB);
        float s = 0.f;
#pragma unroll
        for (int i = 0; i < EMB / 4; ++i) {
            float4 v = w4[i];
            s = fmaf(v.x, v.x, s); s = fmaf(v.y, v.y, s);
            s = fmaf(v.z, v.z, s); s = fmaf(v.w, v.w, s);
        }
        ynorm[c] = s;
    }
}

// ---------------------------------------------------------------------------
// Main: fp16 3-TERM split MFMA distance + argmin. NO waitcnt in the loop:
//  - Wl (lo) is NOT staged in LDS: per-tile register loads blr[4][2], issued
//    at iteration START, before this iteration's stage DMA.
//  - Wh staged 3-deep via global_load_lds (stage tile tt+2 each iter).
//  - In-order vmcnt retirement makes the compiler's blr-consumption wait
//    (vmcnt<=11) force stage(tt+1) [older, issued last iter] complete while
//    leaving stage(tt+2) [younger] in flight across the raw s_barrier.
//    This is the T4 counted-wait pipeline expressed purely via reg deps.
// Ends in the fence-free atomic combine (verified r6).
// Session notes (measured):
//  - __launch_bounds__ arg2 = min WORKGROUPS/CU (r2: (512,4) => 64-VGPR spill).
//  - coop grid.sync fusion: 3x slower (r4). __threadfence finisher: +34us (r5).
//  - 8-wave blocks / 4 waves/SIMD: slower than 4-wave blocks (r3).
//  - per-tile vmcnt(0) drain (r1/r6 structure): ~23% issue-nothing stall.
//  - 3-term split + atomic combine verified absmax=0 (r5/r6).
// ---------------------------------------------------------------------------
__global__ __launch_bounds__(TPB, 2) void vq_mfma_kernel(
    const float* __restrict__ X,
    const _Float16* __restrict__ Wh, const _Float16* __restrict__ Wl,
    const float* __restrict__ ynorm,
    unsigned long long* __restrict__ packed,
    int* __restrict__ cnt, int* __restrict__ out)
{
    __shared__ __align__(16) _Float16 LdsH[3][TCH];   // 48KB: 3-deep Wh tiles
    __shared__ __align__(16) float    Lyn[CRANGE];    // 8KB
    __shared__ float RedV[2][BQ];
    __shared__ int   RedI[2][BQ];
    __shared__ int   fin;

    const int t    = threadIdx.x;
    const int lane = t & 63;
    const int wid  = t >> 6;       // 0..3
    const int wq   = wid & 1;      // q half (0/1)
    const int wy   = wid >> 1;     // c half (0/1)
    const int l15  = lane & 15;
    const int lq   = lane >> 4;    // 0..3

    const int bx     = blockIdx.x;
    const int qblk   = bx * BQ;
    const int qbase  = qblk + wq * 64;
    const int cbase0 = blockIdx.y * CRANGE;

    // --- prologue: DMA-stage tiles 0 and 1 (issued first, overlap prologue) ---
#pragma unroll
    for (int pt = 0; pt < 2; ++pt) {
        const size_t gsbase = (size_t)(cbase0 + pt * TILE_C) * 64;   // halves
#pragma unroll
        for (int i = 0; i < 4; ++i) {
            const int jw = i * 256 + wid * 64;                       // wave-uniform
            gl2lds16(Wh + gsbase + (size_t)(jw + lane) * 8, &LdsH[pt][0] + (size_t)jw * 8);
        }
    }

    // --- stage the block's full ynorm range once ---
    for (int u = t; u < CRANGE / 4; u += TPB)
        ((float4*)Lyn)[u] = ((const float4*)(ynorm + cbase0))[u];

    // --- A fragments: X rows (qbase + mt*16 + l15), k = kb*32 + lq*8 + j ---
    half8 ah[4][2], al[4][2];
#pragma unroll
    for (int mt = 0; mt < 4; ++mt) {
#pragma unroll
        for (int kb = 0; kb < 2; ++kb) {
            const float* xp = X + (size_t)(qbase + mt * 16 + l15) * EMB + kb * 32 + lq * 8;
            float4 v0 = *(const float4*)xp;
            float4 v1 = *(const float4*)(xp + 4);
            float xv[8] = {v0.x, v0.y, v0.z, v0.w, v1.x, v1.y, v1.z, v1.w};
            half8 h, l;
#pragma unroll
            for (int j = 0; j < 8; ++j) {
                _Float16 hh = (_Float16)xv[j];
                h[j] = hh;
                l[j] = (_Float16)(xv[j] - (float)hh);
            }
            ah[mt][kb] = h;
            al[mt][kb] = l;
        }
    }

    float minv[4][4];
    int   mini[4][4];
#pragma unroll
    for (int mt = 0; mt < 4; ++mt)
#pragma unroll
        for (int r = 0; r < 4; ++r) { minv[mt][r] = INFINITY; mini[mt][r] = 0; }

    const f32x4 zero4 = {0.f, 0.f, 0.f, 0.f};

    __syncthreads();   // one-time full drain: tiles 0/1 DMA + Lyn visible

    for (int tt = 0; tt < NT; ++tt) {
        const int cb = cbase0 + tt * TILE_C;

        // --- (1) Wl lo-fragments for THIS tile -> regs (issued before stage) ---
        half8 blr[4][2];
#pragma unroll
        for (int ct = 0; ct < 4; ++ct) {
            const size_t gc = (size_t)cb * 8 + (wy * 4 + ct) * 128 + lane;  // chunk id
            blr[ct][0] = *(const half8*)(Wl + gc * 8);
            blr[ct][1] = *(const half8*)(Wl + (gc + 64) * 8);
        }

        // --- (2) stage Wh tile tt+2 (stays in flight across compute+barrier) ---
        if (tt + 2 < NT) {
            const size_t gsbase = (size_t)(cb + 2 * TILE_C) * 64;   // halves
            _Float16* dst = &LdsH[(tt + 2) % 3][0];
#pragma unroll
            for (int i = 0; i < 4; ++i) {
                const int jw = i * 256 + wid * 64;
                gl2lds16(Wh + gsbase + (size_t)(jw + lane) * 8, dst + (size_t)jw * 8);
            }
        }

        // --- (3) compute tile tt from LdsH[tt%3] + blr ---
        const _Float16* LH = &LdsH[tt % 3][0];
        const int c0 = tt * TILE_C;
#pragma unroll
        for (int ct = 0; ct < 4; ++ct) {
            const int chunk0 = (wy * 4 + ct) * 128 + lane;   // 64 consecutive chunks/wave
            half8 bh0 = *(const half8*)(LH + (size_t)chunk0 * 8);
            half8 bh1 = *(const half8*)(LH + (size_t)(chunk0 + 64) * 8);
            f32x4 acc[4];
#pragma unroll
            for (int mt = 0; mt < 4; ++mt) {
                // 3-term: al*bh + ah*bl + ah*bh per kb (verified r5/r6, absmax=0)
                f32x4 a = __builtin_amdgcn_mfma_f32_16x16x32_f16(al[mt][0], bh0, zero4, 0, 0, 0);
                a = __builtin_amdgcn_mfma_f32_16x16x32_f16(ah[mt][0], blr[ct][0], a, 0, 0, 0);
                a = __builtin_amdgcn_mfma_f32_16x16x32_f16(ah[mt][0], bh0, a, 0, 0, 0);
                a = __builtin_amdgcn_mfma_f32_16x16x32_f16(al[mt][1], bh1, a, 0, 0, 0);
                a = __builtin_amdgcn_mfma_f32_16x16x32_f16(ah[mt][1], blr[ct][1], a, 0, 0, 0);
                a = __builtin_amdgcn_mfma_f32_16x16x32_f16(ah[mt][1], bh1, a, 0, 0, 0);
                acc[mt] = a;
            }
            // --- epilogue: dist = ynorm - 2*dot; running argmin (c ascending, strict <) ---
            const int   ccol = wy * 64 + ct * 16;
            const float yn   = Lyn[c0 + ccol + l15];
            const int   cidx = cb + ccol + l15;
#pragma unroll
            for (int mt = 0; mt < 4; ++mt) {
#pragma unroll
                for (int r = 0; r < 4; ++r) {
                    float s = fmaf(-2.f, acc[mt][r], yn);
                    if (s < minv[mt][r]) { minv[mt][r] = s; mini[mt][r] = cidx; }
                }
            }
        }

        // --- (4) raw barrier only. No vmcnt drain: consuming blr (youngest
        // before stage tt+2) already forced stage tt+1 complete; stage tt+2
        // remains in flight into the next iteration. ---
        __builtin_amdgcn_s_barrier();
    }

    // --- cross-lane: reduce over the 16 col-lanes (xor on low 4 lane bits) ---
#pragma unroll
    for (int mt = 0; mt < 4; ++mt) {
#pragma unroll
        for (int r = 0; r < 4; ++r) {
            float v = minv[mt][r];
            int   i = mini[mt][r];
#pragma unroll
            for (int m = 1; m <= 8; m <<= 1) {
                float ov = __shfl_xor(v, m, 64);
                int   oi = __shfl_xor(i, m, 64);
                if (ov < v || (ov == v && oi < i)) { v = ov; i = oi; }
            }
            if (l15 == 0) {
                int qoff = wq * 64 + mt * 16 + lq * 4 + r;   // row within block
                RedV[wy][qoff] = v;
                RedI[wy][qoff] = i;
            }
        }
    }
    __syncthreads();

    // --- combine c-halves, then FENCE-FREE cross-split combine via atomics ---
    if (t < BQ) {
        float v0 = RedV[0][t]; int i0 = RedI[0][t];
        float v1 = RedV[1][t]; int i1 = RedI[1][t];
        if (v1 < v0 || (v1 == v0 && i1 < i0)) { v0 = v1; i0 = i1; }
        atomicMin(&packed[qblk + t], pack_di(v0, i0));   // device-scope, coherent
    }
    // ensure this block's atomicMins are globally performed before the ticket
    asm volatile("s_waitcnt vmcnt(0)" ::: "memory");
    __syncthreads();
    if (t == 0) fin = (atomicAdd(&cnt[bx], 1) == CSPLIT - 1);
    __syncthreads();
    if (fin && t < BQ) {
        // atomic read-back (atomicMin with identity) -> final packed value
        unsigned long long v = atomicMin(&packed[qblk + t], ~0ull);
        out[qblk + t] = (int)(unsigned int)(v & 0xFFFFFFFFu);
    }
}

// ---------------------------------------------------------------------------
extern "C" void kernel_launch(void* const* d_in, const int* in_sizes, int n_in,
                              void* d_out, int out_size, void* d_ws, size_t ws_size,
                              hipStream_t stream) {
    const float* X = (const float*)d_in[0];   // [16384, 64]
    const float* W = (const float*)d_in[1];   // [8192, 64]

    // ws layout: Wh(1MB) | Wl(1MB) | ynorm(32KB) | packed(128KB) | cnt(512B)
    _Float16* Wh    = (_Float16*)d_ws;
    _Float16* Wl    = Wh + (size_t)NTOK * EMB;
    float*    ynorm = (float*)(Wl + (size_t)NTOK * EMB);
    unsigned long long* packed = (unsigned long long*)(ynorm + NTOK);
    int*      cnt   = (int*)(packed + NQ);
    int*      out   = (int*)d_out;

    prep_kernel<<<(NTOK * 8 + NTOK) / TPB, TPB, 0, stream>>>(W, Wh, Wl, ynorm, packed, cnt);
    dim3 grid(NXBLK, CSPLIT);
    vq_mfma_kernel<<<grid, TPB, 0, stream>>>(X, Wh, Wl, ynorm, packed, cnt, out);
}